// Round 8
// baseline (76.047 us; speedup 1.0000x reference)
//
#include <hip/hip_runtime.h>
#include <stdint.h>

#define NB 2048
#define NCLASSES 80
#define CONF_T 0.05f
#define IOU_T 0.5f
#define MAX_DET 100
#define MAX_PER_CLASS 100

typedef unsigned long long u64;
typedef unsigned int u32;

__device__ __forceinline__ u64 shfl_xor_u64(u64 v, int mask) {
    int lo = (int)(u32)v, hi = (int)(u32)(v >> 32);
    lo = __shfl_xor(lo, mask, 64);
    hi = __shfl_xor(hi, mask, 64);
    return ((u64)(u32)hi << 32) | (u32)lo;
}

// ====================================================================
// K1 (512 thr/batch): hybrid bitonic sort, 4 elems/thread (validated
// round-6 structure), then class-bucket the sorted keys.
// ====================================================================
__global__ __launch_bounds__(512) void k1_sort(const float* __restrict__ pred,
                                               u64* __restrict__ keysG,
                                               u64* __restrict__ keyBuck,
                                               int* __restrict__ clsOffG,
                                               int* __restrict__ clsCntG) {
    const int b = blockIdx.x, tid = threadIdx.x;
    const int lane = tid & 63, wave = tid >> 6;          // 8 waves
    __shared__ u64 keys[NB];                             // 16 KB
    __shared__ short kcls[NB];                           // 4 KB
    __shared__ int clsCnt[NCLASSES], clsOff[NCLASSES], clsFill[NCLASSES];
    const float* P = pred + (size_t)b * NB * 6;

    if (tid < NCLASSES) { clsCnt[tid] = 0; clsFill[tid] = 0; }

    const int sbase = wave * 256;
    const int iA = sbase + lane, iB = iA + 64, iC = iA + 128, iD = iA + 192;

    auto mkkey = [&](int i) -> u64 {
        float s = P[i * 6 + 5];
        return (s > CONF_T) ? (((u64)__float_as_uint(s) << 32) | (u32)i)
                            : (u64)(u32)i;
    };
    u64 A = mkkey(iA), B = mkkey(iB), C = mkkey(iC), D = mkkey(iD);

    auto loc = [&](u64& X, u64& Y, int ix, int k) {
        bool up = ((ix & k) == 0);
        u64 mx = X > Y ? X : Y, mn = X > Y ? Y : X;
        X = up ? mx : mn; Y = up ? mn : mx;
    };
    auto shf = [&](u64& V, int iv, int j, int k) {
        u64 p = shfl_xor_u64(V, j);
        bool low = ((lane & j) == 0);
        bool up  = ((iv & k) == 0);
        V = (low == up) ? (V > p ? V : p) : (V < p ? V : p);
    };
    auto tail = [&](int k, int jstart) {
        if (jstart >= 128) { loc(A, C, iA, k); loc(B, D, iB, k); }
        if (jstart >= 64)  { loc(A, B, iA, k); loc(C, D, iC, k); }
        for (int j = (jstart > 32 ? 32 : jstart); j >= 1; j >>= 1) {
            shf(A, iA, j, k); shf(B, iB, j, k); shf(C, iC, j, k); shf(D, iD, j, k);
        }
    };

    for (int k = 2; k <= 256; k <<= 1) tail(k, k >> 1);
    keys[iA] = A; keys[iB] = B; keys[iC] = C; keys[iD] = D;
    __syncthreads();

    for (int k = 512; k <= NB; k <<= 1) {
        for (int j = k >> 1; j >= 256; j >>= 1) {
            for (int pp = tid; pp < (NB >> 1); pp += 512) {
                int i1 = ((pp & ~(j - 1)) << 1) | (pp & (j - 1));
                int i2 = i1 + j;
                bool up = ((i1 & k) == 0);
                u64 a = keys[i1], c = keys[i2];
                if (up ? (a < c) : (a > c)) { keys[i1] = c; keys[i2] = a; }
            }
            __syncthreads();
        }
        A = keys[iA]; B = keys[iB]; C = keys[iC]; D = keys[iD];
        tail(k, 128);
        keys[iA] = A; keys[iB] = B; keys[iC] = C; keys[iD] = D;
        __syncthreads();
    }

    // ---- class pass: classes + counts ----
    for (int i = tid; i < NB; i += 512) {
        u64 k = keys[i];
        int c = -1;
        if (k >> 32) { c = (int)P[(int)(u32)k * 6 + 4]; atomicAdd(&clsCnt[c], 1); }
        kcls[i] = (short)c;
    }
    __syncthreads();
    // ---- wave-parallel exclusive prefix over 80 class counts ----
    if (wave == 0) {
        int v0 = clsCnt[lane];
        int v1 = (lane < NCLASSES - 64) ? clsCnt[64 + lane] : 0;
        int s0 = v0;
        #pragma unroll
        for (int d = 1; d < 64; d <<= 1) { int t = __shfl_up(s0, d, 64); if (lane >= d) s0 += t; }
        int tot0 = __shfl(s0, 63, 64);
        int s1 = v1;
        #pragma unroll
        for (int d = 1; d < 16; d <<= 1) { int t = __shfl_up(s1, d, 64); if (lane >= d) s1 += t; }
        clsOff[lane] = s0 - v0;
        if (lane < NCLASSES - 64) clsOff[64 + lane] = tot0 + (s1 - v1);
    }
    __syncthreads();
    // ---- scatter (order within bucket irrelevant; k2 re-sorts) ----
    for (int i = tid; i < NB; i += 512) {
        keysG[(size_t)b * NB + i] = keys[i];
        int c = kcls[i];
        if (c >= 0) {
            int p = clsOff[c] + atomicAdd(&clsFill[c], 1);
            keyBuck[(size_t)b * NB + p] = keys[i];
        }
    }
    if (tid < NCLASSES) {
        clsCntG[b * NCLASSES + tid] = clsCnt[tid];
        clsOffG[b * NCLASSES + tid] = clsOff[tid];
    }
}

// ====================================================================
// K2 (1024 thr/batch, 16 waves): per-class greedy NMS (wave w owns
// classes w, w+16, ...) -> LDS suppression bitmap -> one barrier ->
// compaction + output. No global bitmap, no memset dispatch.
// ====================================================================
__global__ __launch_bounds__(1024) void k2_nms_out(const float* __restrict__ pred,
                                                   const u64* __restrict__ keysG,
                                                   const u64* __restrict__ keyBuck,
                                                   const int* __restrict__ clsOffG,
                                                   const int* __restrict__ clsCntG,
                                                   float* __restrict__ out, int B) {
    const int b = blockIdx.x, tid = threadIdx.x;
    const int lane = tid & 63, wave = tid >> 6;          // 16 waves
    __shared__ u32 sm[64];                               // 2048-bit suppression bitmap
    __shared__ u64 keptM[32];
    __shared__ int kcnt[32], kbase[32];
    __shared__ unsigned char fstate[NB];                 // cnt>64 fallback only
    const float* P = pred + (size_t)b * NB * 6;

    if (tid < 64) sm[tid] = 0u;
    __syncthreads();

    // ---- NMS phase: wave w handles classes w, w+16, ... (5 each) ----
    for (int c = wave; c < NCLASSES; c += 16) {
        const int cnt = clsCntG[b * NCLASSES + c];
        if (cnt < 2) continue;
        const int off = clsOffG[b * NCLASSES + c];
        const u64* kb = keyBuck + (size_t)b * NB + off;

        if (cnt <= 64) {
            // in-wave descending bitonic sort (validated network)
            u64 v = (lane < cnt) ? kb[lane] : 0ull;
            for (int k = 2; k <= 64; k <<= 1)
                for (int j = k >> 1; j >= 1; j >>= 1) {
                    u64 p = shfl_xor_u64(v, j);
                    bool low = (lane & j) == 0, up = (lane & k) == 0;
                    v = (low == up) ? (v > p ? v : p) : (v < p ? v : p);
                }
            int orig = (int)(u32)v;
            float x1 = 0.f, y1 = 0.f, x2 = 0.f, y2 = 0.f, ar = 0.f;
            if (lane < cnt) {
                const float* q = P + orig * 6;
                x1 = q[0]; y1 = q[1]; x2 = q[2]; y2 = q[3];
                ar = fmaxf(x2 - x1, 0.f) * fmaxf(y2 - y1, 0.f);
            }
            u64 aliveM = __ballot(lane < cnt);
            for (int a = 0; a + 1 < cnt; ++a) {
                if (!((aliveM >> a) & 1ull)) continue;   // uniform within wave
                float ax1 = __shfl(x1, a, 64), ay1 = __shfl(y1, a, 64);
                float ax2 = __shfl(x2, a, 64), ay2 = __shfl(y2, a, 64);
                float aar = __shfl(ar, a, 64);
                bool kill = false;
                if (lane > a && ((aliveM >> lane) & 1ull)) {
                    float ix1 = fmaxf(ax1, x1), iy1 = fmaxf(ay1, y1);
                    float ix2 = fminf(ax2, x2), iy2 = fminf(ay2, y2);
                    float inter = fmaxf(ix2 - ix1, 0.f) * fmaxf(iy2 - iy1, 0.f);
                    float uni = aar + ar - inter;
                    kill = inter / fmaxf(uni, 1e-8f) > IOU_T;
                }
                aliveM &= ~__ballot(kill);
            }
            if (lane < cnt && !((aliveM >> lane) & 1ull))
                atomicOr(&sm[orig >> 5], 1u << (orig & 31));
        } else {
            // ---- exact wave-local fallback (statistically never taken) ----
            volatile unsigned char* vf = fstate + off;   // per-class disjoint range
            for (int e = lane; e < cnt; e += 64) vf[e] = 0;
            __builtin_amdgcn_wave_barrier();
            int keptCount = 0;
            for (;;) {
                u64 best = 0ull; int bi = -1;
                for (int e = lane; e < cnt; e += 64)
                    if (vf[e] == 0) { u64 kv = kb[e]; if (kv > best) { best = kv; bi = e; } }
                for (int d = 32; d >= 1; d >>= 1) {
                    u64 ob = shfl_xor_u64(best, d);
                    int obi = __shfl_xor(bi, d, 64);
                    if (ob > best) { best = ob; bi = obi; }
                }
                if (best == 0ull) break;
                keptCount++;
                int orig = (int)(u32)best;
                const float* q = P + orig * 6;
                float ax1 = q[0], ay1 = q[1], ax2 = q[2], ay2 = q[3];
                float aar = fmaxf(ax2 - ax1, 0.f) * fmaxf(ay2 - ay1, 0.f);
                if (lane == 0) vf[bi] = 1;
                __builtin_amdgcn_wave_barrier();
                for (int e = lane; e < cnt; e += 64) {
                    if (vf[e] == 0) {
                        u64 kv = kb[e];
                        int o2 = (int)(u32)kv;
                        const float* q2 = P + o2 * 6;
                        float bx1 = q2[0], by1 = q2[1], bx2 = q2[2], by2 = q2[3];
                        float br = fmaxf(bx2 - bx1, 0.f) * fmaxf(by2 - by1, 0.f);
                        float ix1 = fmaxf(ax1, bx1), iy1 = fmaxf(ay1, by1);
                        float ix2 = fminf(ax2, bx2), iy2 = fminf(ay2, by2);
                        float inter = fmaxf(ix2 - ix1, 0.f) * fmaxf(iy2 - iy1, 0.f);
                        if (inter / fmaxf(aar + br - inter, 1e-8f) > IOU_T) {
                            vf[e] = 2;
                            atomicOr(&sm[o2 >> 5], 1u << (o2 & 31));
                        }
                    }
                }
                if (keptCount > MAX_PER_CLASS && lane == 0)   // cap: NMS-kept, output-dropped
                    atomicOr(&sm[orig >> 5], 1u << (orig & 31));
                __builtin_amdgcn_wave_barrier();
            }
        }
    }
    __syncthreads();

    // ---- compaction over sorted keys (validated round-6 logic) ----
    const u64* kg = keysG + (size_t)b * NB;
    for (int cc = wave; cc < 32; cc += 16) {
        u64 k = kg[cc * 64 + lane];
        int orig = (int)(u32)k;
        bool kp = ((k >> 32) != 0) && !((sm[orig >> 5] >> (orig & 31)) & 1u);
        u64 m = __ballot(kp);
        if (lane == 0) { keptM[cc] = m; kcnt[cc] = __popcll(m); }
    }
    __syncthreads();
    if (tid < 32) {
        int s = 0;
        for (int c2 = 0; c2 < tid; ++c2) s += kcnt[c2];
        kbase[tid] = s;
    }
    __syncthreads();

    float* boxes_out   = out + (size_t)b * MAX_DET * 4;
    float* scores_out  = out + (size_t)B * MAX_DET * 4 + (size_t)b * MAX_DET;
    float* classes_out = out + (size_t)B * MAX_DET * 5 + (size_t)b * MAX_DET;
    float* numdet_out  = out + (size_t)B * MAX_DET * 6 + b;

    for (int cc = wave; cc < 32; cc += 16) {
        u64 m = keptM[cc];
        bool kp = (m >> lane) & 1ull;
        int pos = kbase[cc] + __popcll(m & ((1ull << lane) - 1ull));
        if (kp && pos < MAX_DET) {
            u64 k = kg[cc * 64 + lane];
            int orig = (int)(u32)k;
            const float* q = P + orig * 6;
            boxes_out[pos * 4 + 0] = q[0];
            boxes_out[pos * 4 + 1] = q[1];
            boxes_out[pos * 4 + 2] = q[2];
            boxes_out[pos * 4 + 3] = q[3];
            scores_out[pos]  = __uint_as_float((u32)(k >> 32));
            classes_out[pos] = q[4];
        }
    }
    int total = kbase[31] + kcnt[31];
    int nd = total < MAX_DET ? total : MAX_DET;
    for (int p = nd + tid; p < MAX_DET; p += 1024) {
        boxes_out[p * 4 + 0] = 0.f;
        boxes_out[p * 4 + 1] = 0.f;
        boxes_out[p * 4 + 2] = 0.f;
        boxes_out[p * 4 + 3] = 0.f;
        scores_out[p]  = 0.f;
        classes_out[p] = 0.f;
    }
    if (tid == 0) *numdet_out = (float)nd;
}

// ====================================================================
// Fallback (round-0 monolithic, validated) if ws is too small.
// ====================================================================
__global__ __launch_bounds__(1024) void nms_fallback(const float* __restrict__ pred,
                                                     float* __restrict__ out, int B) {
    const int b = blockIdx.x, tid = threadIdx.x;
    __shared__ u64 keys[NB];
    __shared__ float bx1[NB], by1[NB], bx2[NB], by2[NB];
    __shared__ int kc[NB];
    __shared__ int cnt[NCLASSES];
    __shared__ int overflow;
    const float* P = pred + (size_t)b * NB * 6;
    for (int i = tid; i < NB; i += 1024) {
        float s = P[i * 6 + 5];
        keys[i] = (s > CONF_T) ? (((u64)__float_as_uint(s) << 32) | (uint32_t)i)
                               : (u64)(uint32_t)i;
    }
    __syncthreads();
    for (int k = 2; k <= NB; k <<= 1)
        for (int j = k >> 1; j > 0; j >>= 1) {
            for (int i = tid; i < NB; i += 1024) {
                int ixj = i ^ j;
                if (ixj > i) {
                    u64 a = keys[i], c = keys[ixj];
                    bool up = ((i & k) == 0);
                    if (up ? (a < c) : (a > c)) { keys[i] = c; keys[ixj] = a; }
                }
            }
            __syncthreads();
        }
    for (int i = tid; i < NB; i += 1024) {
        u64 k = keys[i];
        int orig = (int)(uint32_t)k;
        const float* q = P + orig * 6;
        bx1[i] = q[0]; by1[i] = q[1]; bx2[i] = q[2]; by2[i] = q[3];
        kc[i] = ((k >> 32) != 0) ? (int)q[4] : -1;
    }
    __syncthreads();
    bool dirty = false;
    for (int i = 0; i < NB - 1; ++i) {
        if (i == 0 || dirty) { __syncthreads(); dirty = false; }
        int ci = kc[i];
        if (ci < 0) continue;
        dirty = true;
        float x1i = bx1[i], y1i = by1[i], x2i = bx2[i], y2i = by2[i];
        float ai = fmaxf(x2i - x1i, 0.f) * fmaxf(y2i - y1i, 0.f);
        for (int j = i + 1 + tid; j < NB; j += 1024) {
            if (kc[j] != ci) continue;
            float ix1 = fmaxf(x1i, bx1[j]), iy1 = fmaxf(y1i, by1[j]);
            float ix2 = fminf(x2i, bx2[j]), iy2 = fminf(y2i, by2[j]);
            float inter = fmaxf(ix2 - ix1, 0.f) * fmaxf(iy2 - iy1, 0.f);
            float aj = fmaxf(bx2[j] - bx1[j], 0.f) * fmaxf(by2[j] - by1[j], 0.f);
            if (inter / fmaxf(ai + aj - inter, 1e-8f) > IOU_T) kc[j] = -1;
        }
    }
    __syncthreads();
    for (int i = tid; i < NCLASSES; i += 1024) cnt[i] = 0;
    if (tid == 0) overflow = 0;
    __syncthreads();
    for (int i = tid; i < NB; i += 1024) if (kc[i] >= 0) atomicAdd(&cnt[kc[i]], 1);
    __syncthreads();
    if (tid < NCLASSES && cnt[tid] > MAX_PER_CLASS) atomicOr(&overflow, 1);
    __syncthreads();
    if (overflow) {
        if (tid == 0) {
            for (int c = 0; c < NCLASSES; ++c) cnt[c] = 0;
            for (int i = 0; i < NB; ++i)
                if (kc[i] >= 0 && ++cnt[kc[i]] > MAX_PER_CLASS) kc[i] = -1;
        }
        __syncthreads();
    }
    if (tid < 64) {
        const int lane = tid;
        float* boxes_out   = out + (size_t)b * MAX_DET * 4;
        float* scores_out  = out + (size_t)B * MAX_DET * 4 + (size_t)b * MAX_DET;
        float* classes_out = out + (size_t)B * MAX_DET * 5 + (size_t)b * MAX_DET;
        float* numdet_out  = out + (size_t)B * MAX_DET * 6 + b;
        int running = 0;
        for (int chunk = 0; chunk < NB / 64; ++chunk) {
            int j = chunk * 64 + lane;
            int c = kc[j];
            bool k = (c >= 0);
            u64 m = __ballot(k);
            int pos = running + __popcll(m & ((1ull << lane) - 1ull));
            if (k && pos < MAX_DET) {
                boxes_out[pos * 4 + 0] = bx1[j];
                boxes_out[pos * 4 + 1] = by1[j];
                boxes_out[pos * 4 + 2] = bx2[j];
                boxes_out[pos * 4 + 3] = by2[j];
                scores_out[pos]  = __uint_as_float((uint32_t)(keys[j] >> 32));
                classes_out[pos] = (float)c;
            }
            running += __popcll(m);
        }
        int nd = running < MAX_DET ? running : MAX_DET;
        for (int p = nd + lane; p < MAX_DET; p += 64) {
            boxes_out[p * 4 + 0] = 0.f; boxes_out[p * 4 + 1] = 0.f;
            boxes_out[p * 4 + 2] = 0.f; boxes_out[p * 4 + 3] = 0.f;
            scores_out[p] = 0.f; classes_out[p] = 0.f;
        }
        if (lane == 0) *numdet_out = (float)nd;
    }
}

extern "C" void kernel_launch(void* const* d_in, const int* in_sizes, int n_in,
                              void* d_out, int out_size, void* d_ws, size_t ws_size,
                              hipStream_t stream) {
    const float* pred = (const float*)d_in[0];
    float* out = (float*)d_out;
    const int B = in_sizes[0] / (NB * 6);
    const size_t nBox = (size_t)B * NB;

    char* base = (char*)d_ws;
    u64* keysG   = (u64*)base;   base += nBox * 8;
    u64* keyBuck = (u64*)base;   base += nBox * 8;
    int* clsOffG = (int*)base;   base += (size_t)B * NCLASSES * 4;
    int* clsCntG = (int*)base;   base += (size_t)B * NCLASSES * 4;
    size_t need = (size_t)(base - (char*)d_ws);

    if (ws_size < need) {
        nms_fallback<<<B, 1024, 0, stream>>>(pred, out, B);
        return;
    }

    k1_sort<<<B, 512, 0, stream>>>(pred, keysG, keyBuck, clsOffG, clsCntG);
    k2_nms_out<<<B, 1024, 0, stream>>>(pred, keysG, keyBuck, clsOffG, clsCntG, out, B);
}

// Round 9
// 37.861 us; speedup vs baseline: 2.0086x; 2.0086x over previous
//
#include <hip/hip_runtime.h>
#include <stdint.h>

#define NB 2048
#define NCLASSES 80
#define CONF_T 0.05f
#define IOU_T 0.5f
#define MAX_DET 100
#define MAX_PER_CLASS 100

typedef unsigned long long u64;
typedef unsigned int u32;

__device__ __forceinline__ u64 shfl_xor_u64(u64 v, int mask) {
    int lo = (int)(u32)v, hi = (int)(u32)(v >> 32);
    lo = __shfl_xor(lo, mask, 64);
    hi = __shfl_xor(hi, mask, 64);
    return ((u64)(u32)hi << 32) | (u32)lo;
}

// ====================================================================
// K1 (512 thr/batch): hybrid bitonic sort + class bucket (validated
// round-6 kernel, unchanged except: zeroes the suppression bitmap).
// ====================================================================
__global__ __launch_bounds__(512) void k1_sort(const float* __restrict__ pred,
                                               u64* __restrict__ keysG,
                                               u64* __restrict__ keyBuck,
                                               int* __restrict__ clsOffG,
                                               int* __restrict__ clsCntG,
                                               u32* __restrict__ supMaskG) {
    const int b = blockIdx.x, tid = threadIdx.x;
    const int lane = tid & 63, wave = tid >> 6;          // 8 waves
    __shared__ u64 keys[NB];                             // 16 KB
    __shared__ short kcls[NB];                           // 4 KB
    __shared__ int clsCnt[NCLASSES], clsOff[NCLASSES], clsFill[NCLASSES];
    const float* P = pred + (size_t)b * NB * 6;

    if (tid < NCLASSES) { clsCnt[tid] = 0; clsFill[tid] = 0; }
    if (tid < 64) supMaskG[b * 64 + tid] = 0u;

    const int sbase = wave * 256;
    const int iA = sbase + lane, iB = iA + 64, iC = iA + 128, iD = iA + 192;

    auto mkkey = [&](int i) -> u64 {
        float s = P[i * 6 + 5];
        return (s > CONF_T) ? (((u64)__float_as_uint(s) << 32) | (u32)i)
                            : (u64)(u32)i;
    };
    u64 A = mkkey(iA), B = mkkey(iB), C = mkkey(iC), D = mkkey(iD);

    auto loc = [&](u64& X, u64& Y, int ix, int k) {
        bool up = ((ix & k) == 0);
        u64 mx = X > Y ? X : Y, mn = X > Y ? Y : X;
        X = up ? mx : mn; Y = up ? mn : mx;
    };
    auto shf = [&](u64& V, int iv, int j, int k) {
        u64 p = shfl_xor_u64(V, j);
        bool low = ((lane & j) == 0);
        bool up  = ((iv & k) == 0);
        V = (low == up) ? (V > p ? V : p) : (V < p ? V : p);
    };
    auto tail = [&](int k, int jstart) {
        if (jstart >= 128) { loc(A, C, iA, k); loc(B, D, iB, k); }
        if (jstart >= 64)  { loc(A, B, iA, k); loc(C, D, iC, k); }
        for (int j = (jstart > 32 ? 32 : jstart); j >= 1; j >>= 1) {
            shf(A, iA, j, k); shf(B, iB, j, k); shf(C, iC, j, k); shf(D, iD, j, k);
        }
    };

    for (int k = 2; k <= 256; k <<= 1) tail(k, k >> 1);
    keys[iA] = A; keys[iB] = B; keys[iC] = C; keys[iD] = D;
    __syncthreads();

    for (int k = 512; k <= NB; k <<= 1) {
        for (int j = k >> 1; j >= 256; j >>= 1) {
            for (int pp = tid; pp < (NB >> 1); pp += 512) {
                int i1 = ((pp & ~(j - 1)) << 1) | (pp & (j - 1));
                int i2 = i1 + j;
                bool up = ((i1 & k) == 0);
                u64 a = keys[i1], c = keys[i2];
                if (up ? (a < c) : (a > c)) { keys[i1] = c; keys[i2] = a; }
            }
            __syncthreads();
        }
        A = keys[iA]; B = keys[iB]; C = keys[iC]; D = keys[iD];
        tail(k, 128);
        keys[iA] = A; keys[iB] = B; keys[iC] = C; keys[iD] = D;
        __syncthreads();
    }

    for (int i = tid; i < NB; i += 512) {
        u64 k = keys[i];
        int c = -1;
        if (k >> 32) { c = (int)P[(int)(u32)k * 6 + 4]; atomicAdd(&clsCnt[c], 1); }
        kcls[i] = (short)c;
    }
    __syncthreads();
    if (wave == 0) {
        int v0 = clsCnt[lane];
        int v1 = (lane < NCLASSES - 64) ? clsCnt[64 + lane] : 0;
        int s0 = v0;
        #pragma unroll
        for (int d = 1; d < 64; d <<= 1) { int t = __shfl_up(s0, d, 64); if (lane >= d) s0 += t; }
        int tot0 = __shfl(s0, 63, 64);
        int s1 = v1;
        #pragma unroll
        for (int d = 1; d < 16; d <<= 1) { int t = __shfl_up(s1, d, 64); if (lane >= d) s1 += t; }
        clsOff[lane] = s0 - v0;
        if (lane < NCLASSES - 64) clsOff[64 + lane] = tot0 + (s1 - v1);
    }
    __syncthreads();
    for (int i = tid; i < NB; i += 512) {
        keysG[(size_t)b * NB + i] = keys[i];
        int c = kcls[i];
        if (c >= 0) {
            int p = clsOff[c] + atomicAdd(&clsFill[c], 1);
            keyBuck[(size_t)b * NB + p] = keys[i];
        }
    }
    if (tid < NCLASSES) {
        clsCntG[b * NCLASSES + tid] = clsCnt[tid];
        clsOffG[b * NCLASSES + tid] = clsOff[tid];
    }
}

// ====================================================================
// K2 (one wave per (class,batch)): SORT-FREE pair-matrix NMS.
// Lane j builds mj = bitmask of lanes i whose key > key_j (exact
// global order, keys unique) and IoU > T, via 64 independent LDS
// broadcast reads (pipelined, no cross-lane chain). One ballot: if no
// lane has mj!=0, nothing is suppressed (common case). Else a tiny
// redundant scalar greedy over the conflict set resolves exactly.
// ====================================================================
__global__ __launch_bounds__(64) void k2_nms(const float* __restrict__ pred,
                                             const u64* __restrict__ keyBuck,
                                             const int* __restrict__ clsOffG,
                                             const int* __restrict__ clsCntG,
                                             u32* __restrict__ supMaskG) {
    const int c = blockIdx.x, b = blockIdx.y, lane = threadIdx.x;
    __shared__ u64 wkey[64];
    __shared__ float4 wbox[64];
    __shared__ u64 wm[64];
    __shared__ unsigned char fstate[NB];     // cnt>64 fallback only
    const int cnt = clsCntG[b * NCLASSES + c];
    if (cnt < 2) return;
    const int off = clsOffG[b * NCLASSES + c];
    const float* P = pred + (size_t)b * NB * 6;
    const u64* kb = keyBuck + (size_t)b * NB + off;

    if (cnt <= 64) {
        u64 mykey = 0ull;
        float x1 = 0.f, y1 = 0.f, x2 = 0.f, y2 = 0.f, ar = 0.f;
        int orig = 0;
        if (lane < cnt) {
            mykey = kb[lane];
            orig = (int)(u32)mykey;
            const float* q = P + orig * 6;
            float2 p01 = *reinterpret_cast<const float2*>(q);
            float2 p23 = *reinterpret_cast<const float2*>(q + 2);
            x1 = p01.x; y1 = p01.y; x2 = p23.x; y2 = p23.y;
            ar = fmaxf(x2 - x1, 0.f) * fmaxf(y2 - y1, 0.f);
        }
        wkey[lane] = mykey;                   // 0 for lanes >= cnt
        wbox[lane] = make_float4(x1, y1, x2, y2);
        __syncthreads();

        u64 mj = 0ull;
        if (lane < cnt) {
            #pragma unroll 8
            for (int i = 0; i < 64; ++i) {
                u64 ki = wkey[i];
                if (ki > mykey) {             // i precedes j in exact global order
                    float4 bi = wbox[i];
                    float ari = fmaxf(bi.z - bi.x, 0.f) * fmaxf(bi.w - bi.y, 0.f);
                    float ix1 = fmaxf(bi.x, x1), iy1 = fmaxf(bi.y, y1);
                    float ix2 = fminf(bi.z, x2), iy2 = fminf(bi.w, y2);
                    float inter = fmaxf(ix2 - ix1, 0.f) * fmaxf(iy2 - iy1, 0.f);
                    float uni = ari + ar - inter;
                    if (inter / fmaxf(uni, 1e-8f) > IOU_T) mj |= 1ull << i;
                }
            }
        }
        u64 conf = __ballot(mj != 0ull);
        if (conf == 0ull) return;             // nothing can be suppressed

        // sources = union of mj over lanes
        u64 srcs = mj;
        #pragma unroll
        for (int d = 1; d < 64; d <<= 1) srcs |= shfl_xor_u64(srcs, d);
        wm[lane] = mj;
        __syncthreads();

        // redundant scalar greedy over conflict set C (desc key order)
        u64 Cset = srcs | conf;
        u64 keptS = 0ull, rem = Cset;
        while (rem) {
            u64 t = rem, bestk = 0ull; int bi = -1;
            while (t) {
                int i = __ffsll(t) - 1; t &= t - 1;
                u64 k = wkey[i];
                if (k > bestk) { bestk = k; bi = i; }
            }
            rem &= ~(1ull << bi);
            if ((wm[bi] & keptS) == 0ull) keptS |= 1ull << bi;  // kept
        }
        if (lane < cnt && (mj & keptS) != 0ull)
            atomicOr(&supMaskG[b * 64 + (orig >> 5)], 1u << (orig & 31));
    } else {
        // ---- exact selection-greedy fallback (validated R8 path) ----
        volatile unsigned char* vf = fstate;
        for (int e = lane; e < cnt; e += 64) vf[e] = 0;
        __syncthreads();
        int keptCount = 0;
        for (;;) {
            u64 best = 0ull; int bi = -1;
            for (int e = lane; e < cnt; e += 64)
                if (vf[e] == 0) { u64 kv = kb[e]; if (kv > best) { best = kv; bi = e; } }
            for (int d = 32; d >= 1; d >>= 1) {
                u64 ob = shfl_xor_u64(best, d);
                int obi = __shfl_xor(bi, d, 64);
                if (ob > best) { best = ob; bi = obi; }
            }
            if (best == 0ull) break;
            keptCount++;
            int orig = (int)(u32)best;
            const float* q = P + orig * 6;
            float ax1 = q[0], ay1 = q[1], ax2 = q[2], ay2 = q[3];
            float aar = fmaxf(ax2 - ax1, 0.f) * fmaxf(ay2 - ay1, 0.f);
            if (lane == 0) vf[bi] = 1;
            __syncthreads();
            for (int e = lane; e < cnt; e += 64) {
                if (vf[e] == 0) {
                    u64 kv = kb[e];
                    int o2 = (int)(u32)kv;
                    const float* q2 = P + o2 * 6;
                    float bx1 = q2[0], by1 = q2[1], bx2 = q2[2], by2 = q2[3];
                    float br = fmaxf(bx2 - bx1, 0.f) * fmaxf(by2 - by1, 0.f);
                    float ix1 = fmaxf(ax1, bx1), iy1 = fmaxf(ay1, by1);
                    float ix2 = fminf(ax2, bx2), iy2 = fminf(ay2, by2);
                    float inter = fmaxf(ix2 - ix1, 0.f) * fmaxf(iy2 - iy1, 0.f);
                    if (inter / fmaxf(aar + br - inter, 1e-8f) > IOU_T) {
                        vf[e] = 2;
                        atomicOr(&supMaskG[b * 64 + (o2 >> 5)], 1u << (o2 & 31));
                    }
                }
            }
            if (keptCount > MAX_PER_CLASS && lane == 0)
                atomicOr(&supMaskG[b * 64 + (orig >> 5)], 1u << (orig & 31));
            __syncthreads();
        }
    }
}

// ====================================================================
// K3 (per batch, 256 thr): bitmap -> compaction -> output (validated
// round-6/7 logic).
// ====================================================================
__global__ __launch_bounds__(256) void k3_out(const float* __restrict__ pred,
                                              const u64* __restrict__ keysG,
                                              const u32* __restrict__ supMaskG,
                                              float* __restrict__ out, int B) {
    const int b = blockIdx.x, tid = threadIdx.x;
    const int wave = tid >> 6, lane = tid & 63;
    __shared__ u32 sm[64];
    __shared__ u64 keptM[32];
    __shared__ int kcnt[32], kbase[32];

    if (tid < 64) sm[tid] = supMaskG[b * 64 + tid];
    __syncthreads();

    const u64* kg = keysG + (size_t)b * NB;
    const float* P = pred + (size_t)b * NB * 6;

    for (int cc = wave; cc < 32; cc += 4) {
        u64 k = kg[cc * 64 + lane];
        int orig = (int)(u32)k;
        bool kp = ((k >> 32) != 0) && !((sm[orig >> 5] >> (orig & 31)) & 1u);
        u64 m = __ballot(kp);
        if (lane == 0) { keptM[cc] = m; kcnt[cc] = __popcll(m); }
    }
    __syncthreads();
    if (tid < 32) {
        int s = 0;
        for (int c2 = 0; c2 < tid; ++c2) s += kcnt[c2];
        kbase[tid] = s;
    }
    __syncthreads();

    float* boxes_out   = out + (size_t)b * MAX_DET * 4;
    float* scores_out  = out + (size_t)B * MAX_DET * 4 + (size_t)b * MAX_DET;
    float* classes_out = out + (size_t)B * MAX_DET * 5 + (size_t)b * MAX_DET;
    float* numdet_out  = out + (size_t)B * MAX_DET * 6 + b;

    for (int cc = wave; cc < 32; cc += 4) {
        u64 m = keptM[cc];
        bool kp = (m >> lane) & 1ull;
        int pos = kbase[cc] + __popcll(m & ((1ull << lane) - 1ull));
        if (kp && pos < MAX_DET) {
            u64 k = kg[cc * 64 + lane];
            int orig = (int)(u32)k;
            const float* q = P + orig * 6;
            boxes_out[pos * 4 + 0] = q[0];
            boxes_out[pos * 4 + 1] = q[1];
            boxes_out[pos * 4 + 2] = q[2];
            boxes_out[pos * 4 + 3] = q[3];
            scores_out[pos]  = __uint_as_float((u32)(k >> 32));
            classes_out[pos] = q[4];
        }
    }
    int total = kbase[31] + kcnt[31];
    int nd = total < MAX_DET ? total : MAX_DET;
    for (int p = nd + tid; p < MAX_DET; p += 256) {
        boxes_out[p * 4 + 0] = 0.f;
        boxes_out[p * 4 + 1] = 0.f;
        boxes_out[p * 4 + 2] = 0.f;
        boxes_out[p * 4 + 3] = 0.f;
        scores_out[p]  = 0.f;
        classes_out[p] = 0.f;
    }
    if (tid == 0) *numdet_out = (float)nd;
}

// ====================================================================
// Fallback (round-0 monolithic, validated) if ws is too small.
// ====================================================================
__global__ __launch_bounds__(1024) void nms_fallback(const float* __restrict__ pred,
                                                     float* __restrict__ out, int B) {
    const int b = blockIdx.x, tid = threadIdx.x;
    __shared__ u64 keys[NB];
    __shared__ float bx1[NB], by1[NB], bx2[NB], by2[NB];
    __shared__ int kc[NB];
    __shared__ int cnt[NCLASSES];
    __shared__ int overflow;
    const float* P = pred + (size_t)b * NB * 6;
    for (int i = tid; i < NB; i += 1024) {
        float s = P[i * 6 + 5];
        keys[i] = (s > CONF_T) ? (((u64)__float_as_uint(s) << 32) | (uint32_t)i)
                               : (u64)(uint32_t)i;
    }
    __syncthreads();
    for (int k = 2; k <= NB; k <<= 1)
        for (int j = k >> 1; j > 0; j >>= 1) {
            for (int i = tid; i < NB; i += 1024) {
                int ixj = i ^ j;
                if (ixj > i) {
                    u64 a = keys[i], c = keys[ixj];
                    bool up = ((i & k) == 0);
                    if (up ? (a < c) : (a > c)) { keys[i] = c; keys[ixj] = a; }
                }
            }
            __syncthreads();
        }
    for (int i = tid; i < NB; i += 1024) {
        u64 k = keys[i];
        int orig = (int)(uint32_t)k;
        const float* q = P + orig * 6;
        bx1[i] = q[0]; by1[i] = q[1]; bx2[i] = q[2]; by2[i] = q[3];
        kc[i] = ((k >> 32) != 0) ? (int)q[4] : -1;
    }
    __syncthreads();
    bool dirty = false;
    for (int i = 0; i < NB - 1; ++i) {
        if (i == 0 || dirty) { __syncthreads(); dirty = false; }
        int ci = kc[i];
        if (ci < 0) continue;
        dirty = true;
        float x1i = bx1[i], y1i = by1[i], x2i = bx2[i], y2i = by2[i];
        float ai = fmaxf(x2i - x1i, 0.f) * fmaxf(y2i - y1i, 0.f);
        for (int j = i + 1 + tid; j < NB; j += 1024) {
            if (kc[j] != ci) continue;
            float ix1 = fmaxf(x1i, bx1[j]), iy1 = fmaxf(y1i, by1[j]);
            float ix2 = fminf(x2i, bx2[j]), iy2 = fminf(y2i, by2[j]);
            float inter = fmaxf(ix2 - ix1, 0.f) * fmaxf(iy2 - iy1, 0.f);
            float aj = fmaxf(bx2[j] - bx1[j], 0.f) * fmaxf(by2[j] - by1[j], 0.f);
            if (inter / fmaxf(ai + aj - inter, 1e-8f) > IOU_T) kc[j] = -1;
        }
    }
    __syncthreads();
    for (int i = tid; i < NCLASSES; i += 1024) cnt[i] = 0;
    if (tid == 0) overflow = 0;
    __syncthreads();
    for (int i = tid; i < NB; i += 1024) if (kc[i] >= 0) atomicAdd(&cnt[kc[i]], 1);
    __syncthreads();
    if (tid < NCLASSES && cnt[tid] > MAX_PER_CLASS) atomicOr(&overflow, 1);
    __syncthreads();
    if (overflow) {
        if (tid == 0) {
            for (int c = 0; c < NCLASSES; ++c) cnt[c] = 0;
            for (int i = 0; i < NB; ++i)
                if (kc[i] >= 0 && ++cnt[kc[i]] > MAX_PER_CLASS) kc[i] = -1;
        }
        __syncthreads();
    }
    if (tid < 64) {
        const int lane = tid;
        float* boxes_out   = out + (size_t)b * MAX_DET * 4;
        float* scores_out  = out + (size_t)B * MAX_DET * 4 + (size_t)b * MAX_DET;
        float* classes_out = out + (size_t)B * MAX_DET * 5 + (size_t)b * MAX_DET;
        float* numdet_out  = out + (size_t)B * MAX_DET * 6 + b;
        int running = 0;
        for (int chunk = 0; chunk < NB / 64; ++chunk) {
            int j = chunk * 64 + lane;
            int c = kc[j];
            bool k = (c >= 0);
            u64 m = __ballot(k);
            int pos = running + __popcll(m & ((1ull << lane) - 1ull));
            if (k && pos < MAX_DET) {
                boxes_out[pos * 4 + 0] = bx1[j];
                boxes_out[pos * 4 + 1] = by1[j];
                boxes_out[pos * 4 + 2] = bx2[j];
                boxes_out[pos * 4 + 3] = by2[j];
                scores_out[pos]  = __uint_as_float((uint32_t)(keys[j] >> 32));
                classes_out[pos] = (float)c;
            }
            running += __popcll(m);
        }
        int nd = running < MAX_DET ? running : MAX_DET;
        for (int p = nd + lane; p < MAX_DET; p += 64) {
            boxes_out[p * 4 + 0] = 0.f; boxes_out[p * 4 + 1] = 0.f;
            boxes_out[p * 4 + 2] = 0.f; boxes_out[p * 4 + 3] = 0.f;
            scores_out[p] = 0.f; classes_out[p] = 0.f;
        }
        if (lane == 0) *numdet_out = (float)nd;
    }
}

extern "C" void kernel_launch(void* const* d_in, const int* in_sizes, int n_in,
                              void* d_out, int out_size, void* d_ws, size_t ws_size,
                              hipStream_t stream) {
    const float* pred = (const float*)d_in[0];
    float* out = (float*)d_out;
    const int B = in_sizes[0] / (NB * 6);
    const size_t nBox = (size_t)B * NB;

    char* base = (char*)d_ws;
    u64* keysG    = (u64*)base;  base += nBox * 8;
    u64* keyBuck  = (u64*)base;  base += nBox * 8;
    int* clsOffG  = (int*)base;  base += (size_t)B * NCLASSES * 4;
    int* clsCntG  = (int*)base;  base += (size_t)B * NCLASSES * 4;
    u32* supMaskG = (u32*)base;  base += (size_t)B * 64 * 4;
    size_t need = (size_t)(base - (char*)d_ws);

    if (ws_size < need) {
        nms_fallback<<<B, 1024, 0, stream>>>(pred, out, B);
        return;
    }

    k1_sort<<<B, 512, 0, stream>>>(pred, keysG, keyBuck, clsOffG, clsCntG, supMaskG);
    k2_nms<<<dim3(NCLASSES, B), 64, 0, stream>>>(pred, keyBuck, clsOffG, clsCntG, supMaskG);
    k3_out<<<B, 256, 0, stream>>>(pred, keysG, supMaskG, out, B);
}